// Round 7
// baseline (200.004 us; speedup 1.0000x reference)
//
#include <hip/hip_runtime.h>
#include <hip/hip_bf16.h>

// ============================================================================
// fused stride-2 "transposed conv" + bias + channel-softmax + sigmoid
//
// PAD==OUT_PAD==1 => odd h or odd w outputs are the constant vector
// sigmoid(2*softmax(bias)). Even-even outputs are a dense 4x4 conv:
//   O[n,c,p,q] = sum_{ic,kh,kw} x[n,ic,p-kh,q-kw]*W[c,ic,kh,kw]
//
// R7: R6 + HAND-ROTATED K-loop pipeline. R5/R6 evidence: VGPR=36, all pipes
// <30% => zero prefetch depth; each K-step serially pays ~200cy L2 (W) +
// ~120cy LDS (X) vs 48cy of MFMA. Explicit depth-2 W / depth-1 X register
// prefetch (named locals, loads before MFMAs) gives the scheduler in-flight
// loads to overlap; 4 waves/SIMD x 48cy then covers the L2 latency.
// Numerics: bf16 hi/lo split (Whi*Xhi + Wlo*Xhi + Whi*Xlo), fp32 acc.
// ============================================================================

typedef __bf16 bf16x8 __attribute__((ext_vector_type(8)));
typedef float  f32x4  __attribute__((ext_vector_type(4)));
typedef float  f32x16 __attribute__((ext_vector_type(16)));
typedef unsigned short ushort_t;

#define TILE_P 4
#define TILE_Q 16
#define PATCH_R 7                     // TILE_P + 3
#define PATCH_C 19                    // TILE_Q + 3
#define XELEMS (PATCH_R*PATCH_C*64)   // 8512 bf16 per plane
#define XLO_BYTES (XELEMS*2)          // 17024
#define SMEM_BYTES (XELEMS*2*2)       // 34048 -> 4 blocks/CU
#define WSW_BYTES (16*4*4*2*64*16)    // 524288 bytes of W fragments
#define ODD_ROWS (32*128*64)          // 262144 odd output rows
#define ROWS_PER_BLOCK 97             // ceil(262144/2720)

// ---- prep: weight -> 32x32 fragment order, bf16 hi/lo ----------------------
// frag f = ((tap*4+icg)*4+Mt)*2+hl, 1KB each; lane l holds
// W[cout=Mt*32+(l&31)][ic=icg*16+(l>>5)*8+i]  (A-operand: row=l&31, k slice).
__global__ void prep_w_kernel(const float* __restrict__ w, ushort_t* __restrict__ wsW) {
    int slot = blockIdx.x * 256 + threadIdx.x;      // 32768 slots
    int lane = slot & 63;
    int hl   = (slot >> 6) & 1;
    int Mt   = (slot >> 7) & 3;
    int icg  = (slot >> 9) & 3;
    int tap  = slot >> 11;
    int kh = tap >> 2, kw = tap & 3;
    int cout = Mt * 32 + (lane & 31);
    int icb  = icg * 16 + (lane >> 5) * 8;
    bf16x8 v;
#pragma unroll
    for (int i = 0; i < 8; ++i) {
        float f = w[((cout * 64 + icb + i) * 4 + kh) * 4 + kw];
        __bf16 h = (__bf16)f;
        v[i] = hl ? (__bf16)(f - (float)h) : h;
    }
    *(bf16x8*)(wsW + (size_t)slot * 8) = v;   // slot*16 bytes
}

// ---- prep: const vector sigmoid(2*softmax(bias)) ---------------------------
__global__ void prep_const_kernel(const float* __restrict__ bias, float* __restrict__ wsc) {
    __shared__ float red[128];
    int t = threadIdx.x;
    red[t] = bias[t];
    __syncthreads();
    float m = -3.4e38f;
    for (int i = 0; i < 128; ++i) m = fmaxf(m, red[i]);
    float e = __expf(red[t] - m);
    __syncthreads();
    red[t] = e;
    __syncthreads();
    float s = 0.f;
    for (int i = 0; i < 128; ++i) s += red[i];
    float v = e / s;
    wsc[t] = 1.0f / (1.0f + __expf(-2.0f * v));
}

// ---- main ------------------------------------------------------------------
__launch_bounds__(256, 4)
__global__ void conv_main_kernel(const float* __restrict__ x,
                                 const float* __restrict__ bias,
                                 const ushort_t* __restrict__ wsW,
                                 const float* __restrict__ wsc,
                                 float* __restrict__ out) {
    extern __shared__ char smem[];
    ushort_t* xs = (ushort_t*)smem;

    const int tid = threadIdx.x;
    const int n   = blockIdx.z;
    const int p0  = blockIdx.y * TILE_P;
    const int q0  = blockIdx.x * TILE_Q;

    const int lane = tid & 63;
    const int wv   = tid >> 6;       // wave id = Mtile (32 couts)
    const int l31  = lane & 31;
    const int lhi  = lane >> 5;
    const int qA   = l31 & 15;       // B col -> q offset
    const int dp   = l31 >> 4;       // B col -> p offset within Ntile

    // ---- stage X patch hi+lo, single pass ----------------------------------
    const float* xg = x + (size_t)n * 262144;
    for (int grp = tid; grp < PATCH_R * PATCH_C * 8; grp += 256) {
        int r   = grp / (PATCH_C * 8);
        int rem = grp - r * (PATCH_C * 8);
        int g   = rem / PATCH_C;
        int c   = rem - g * PATCH_C;
        int row = p0 + r - 3;
        int col = q0 + c - 3;
        bool ok = (row >= 0) & (row < 64) & (col >= 0) & (col < 64);
        const float* src = xg + (g * 8) * 4096 + row * 64 + col;
        bf16x8 hi, lo;
#pragma unroll
        for (int i = 0; i < 8; ++i) {
            float f = ok ? src[i * 4096] : 0.0f;
            __bf16 h = (__bf16)f;
            hi[i] = h;
            lo[i] = (__bf16)(f - (float)h);
        }
        int slot = ((r * PATCH_C + c) * 8 + (g ^ (c & 7))) * 8;     // elem idx
        *(bf16x8*)(xs + slot)          = hi;
        *(bf16x8*)(xs + XELEMS + slot) = lo;
    }
    __syncthreads();

    // ---- K loop: 64 Ksteps, explicit depth-2 W / depth-1 X prefetch --------
    f32x16 acc[2];
    acc[0] = (f32x16)(0.0f);
    acc[1] = (f32x16)(0.0f);

    const char* wbase = (const char*)wsW + wv * 2048 + lane * 16;
    const char* xsc   = (const char*)smem;

    auto xaddr = [&](int ks) -> int {
        int tap = ks >> 2, icg = ks & 3;
        int kh = tap >> 2, kw = tap & 3;
        int pc = qA + 3 - kw;
        int pr = dp + 3 - kh;
        int g8 = icg * 2 + lhi;
        return ((((pr * PATCH_C + pc) << 3) + (g8 ^ (pc & 7))) << 4);  // bytes
    };

    // prologue: W for ks=0 (cur) and ks=1 (next); X for ks=0 (cur)
    bf16x8 cwh = *(const bf16x8*)(wbase);
    bf16x8 cwl = *(const bf16x8*)(wbase + 1024);
    bf16x8 nwh = *(const bf16x8*)(wbase + 8192);
    bf16x8 nwl = *(const bf16x8*)(wbase + 8192 + 1024);
    int a0 = xaddr(0);
    bf16x8 cx0h = *(const bf16x8*)(xsc + a0);
    bf16x8 cx0l = *(const bf16x8*)(xsc + a0 + XLO_BYTES);
    bf16x8 cx1h = *(const bf16x8*)(xsc + a0 + 4864);              // +2 p-rows
    bf16x8 cx1l = *(const bf16x8*)(xsc + a0 + 4864 + XLO_BYTES);

#pragma unroll 4
    for (int ks = 0; ks < 64; ++ks) {
        // issue W prefetch for ks+2 (wraps harmlessly at tail)
        const char* wp2 = wbase + ((ks + 2) & 63) * 8192;
        bf16x8 pwh = *(const bf16x8*)(wp2);
        bf16x8 pwl = *(const bf16x8*)(wp2 + 1024);
        // issue X prefetch for ks+1 (wraps harmlessly at tail)
        int a1 = xaddr((ks + 1) & 63);
        bf16x8 nx0h = *(const bf16x8*)(xsc + a1);
        bf16x8 nx0l = *(const bf16x8*)(xsc + a1 + XLO_BYTES);
        bf16x8 nx1h = *(const bf16x8*)(xsc + a1 + 4864);
        bf16x8 nx1l = *(const bf16x8*)(xsc + a1 + 4864 + XLO_BYTES);

        // compute with current registers (loads above are independent)
        acc[0] = __builtin_amdgcn_mfma_f32_32x32x16_bf16(cwh, cx0h, acc[0], 0, 0, 0);
        acc[1] = __builtin_amdgcn_mfma_f32_32x32x16_bf16(cwh, cx1h, acc[1], 0, 0, 0);
        acc[0] = __builtin_amdgcn_mfma_f32_32x32x16_bf16(cwl, cx0h, acc[0], 0, 0, 0);
        acc[1] = __builtin_amdgcn_mfma_f32_32x32x16_bf16(cwl, cx1h, acc[1], 0, 0, 0);
        acc[0] = __builtin_amdgcn_mfma_f32_32x32x16_bf16(cwh, cx0l, acc[0], 0, 0, 0);
        acc[1] = __builtin_amdgcn_mfma_f32_32x32x16_bf16(cwh, cx1l, acc[1], 0, 0, 0);

        // rotate
        cwh = nwh; cwl = nwl; nwh = pwh; nwl = pwl;
        cx0h = nx0h; cx0l = nx0l; cx1h = nx1h; cx1l = nx1l;
    }

    // ---- bias add: channel = wv*32 + (reg&3) + 8*(reg>>2) + 4*lhi ----------
    {
        f32x4 bv[4];
#pragma unroll
        for (int j = 0; j < 4; ++j)
            bv[j] = *(const f32x4*)(bias + wv * 32 + lhi * 4 + j * 8);
#pragma unroll
        for (int nt = 0; nt < 2; ++nt)
#pragma unroll
            for (int reg = 0; reg < 16; ++reg)
                acc[nt][reg] += bv[reg >> 2][reg & 3];
    }

    __syncthreads();                    // X planes dead -> overlay reduce bufs
    float* red1  = (float*)smem;        // [64 pos][4 waves] max
    float* red2  = (float*)(smem + 1024);// [64 pos][4 waves] sum
    float* cfill = (float*)(smem + 2048);// [128] const vector

    if (tid < 128) cfill[tid] = wsc[tid];

    // ---- per-position max: in-lane over 16 regs, shfl over lhi, LDS x4 -----
#pragma unroll
    for (int nt = 0; nt < 2; ++nt) {
        float m = acc[nt][0];
#pragma unroll
        for (int reg = 1; reg < 16; ++reg) m = fmaxf(m, acc[nt][reg]);
        m = fmaxf(m, __shfl_xor(m, 32));
        if (lhi == 0) red1[(nt * 32 + l31) * 4 + wv] = m;
    }
    __syncthreads();

    float gm[2];
#pragma unroll
    for (int nt = 0; nt < 2; ++nt) {
        f32x4 v = *(const f32x4*)&red1[(nt * 32 + l31) * 4];
        gm[nt] = fmaxf(fmaxf(v[0], v[1]), fmaxf(v[2], v[3]));
    }

    // ---- exp + per-position sum --------------------------------------------
#pragma unroll
    for (int nt = 0; nt < 2; ++nt) {
        float s = 0.f;
#pragma unroll
        for (int reg = 0; reg < 16; ++reg) {
            float e = __expf(acc[nt][reg] - gm[nt]);
            acc[nt][reg] = e;
            s += e;
        }
        s += __shfl_xor(s, 32);
        if (lhi == 0) red2[(nt * 32 + l31) * 4 + wv] = s;
    }
    __syncthreads();

    float inv[2];
#pragma unroll
    for (int nt = 0; nt < 2; ++nt) {
        f32x4 v = *(const f32x4*)&red2[(nt * 32 + l31) * 4];
        inv[nt] = 1.0f / (v[0] + v[1] + v[2] + v[3]);
    }

    // ---- normalize, sigmoid, store: 128B-contiguous per 16 lanes -----------
    {
        f32x4 cv[4];
#pragma unroll
        for (int j = 0; j < 4; ++j)
            cv[j] = *(const f32x4*)(wsc + wv * 32 + lhi * 4 + j * 8);

        int q = q0 + qA;
#pragma unroll
        for (int nt = 0; nt < 2; ++nt) {
            int p = p0 + nt * 2 + dp;
            if (p < 65 && q < 65) {
#pragma unroll
                for (int reg = 0; reg < 16; ++reg) {
                    int c = wv * 32 + 4 * lhi + 8 * (reg >> 2) + (reg & 3);
                    float v  = acc[nt][reg] * inv[nt];
                    float sg = 1.0f / (1.0f + __expf(-2.0f * v));
                    size_t o = ((size_t)(n * 128 + c) * 129 + 2 * p) * 129 + 2 * q;
                    if (q < 64) {
                        float2 pr2 = {sg, cv[reg >> 2][reg & 3]};
                        *(float2*)(out + o) = pr2;
                    } else {
                        out[o] = sg;
                    }
                }
            }
        }
    }

    // ---- merged odd-row const fill: 97 FULL 516B rows per block ------------
    {
        int bid   = (blockIdx.z * 17 + blockIdx.y) * 5 + blockIdx.x;
        int rbase = bid * ROWS_PER_BLOCK;
        int t    = tid & 127;           // column 0..127
        int half = tid >> 7;            // 2 rows in flight
        for (int i = half; i < ROWS_PER_BLOCK; i += 2) {
            int r = rbase + i;
            if (r < ODD_ROWS) {
                int n2 = r >> 13;
                int c2 = (r >> 6) & 127;
                int oh = ((r & 63) << 1) + 1;
                float v = cfill[c2];
                size_t base = ((size_t)(n2 * 128 + c2) * 129 + oh) * 129;
                out[base + t] = v;
                if (t == 127) out[base + 128] = v;
            }
        }
    }
}

extern "C" void kernel_launch(void* const* d_in, const int* in_sizes, int n_in,
                              void* d_out, int out_size, void* d_ws, size_t ws_size,
                              hipStream_t stream) {
    const float* x    = (const float*)d_in[0];
    const float* w    = (const float*)d_in[1];
    const float* bias = (const float*)d_in[2];
    float* out = (float*)d_out;

    ushort_t* wsW = (ushort_t*)d_ws;                          // 512 KB
    float* wsc    = (float*)((char*)d_ws + WSW_BYTES);        // 512 B

    (void)hipFuncSetAttribute((const void*)conv_main_kernel,
                              hipFuncAttributeMaxDynamicSharedMemorySize, SMEM_BYTES);

    prep_w_kernel<<<128, 256, 0, stream>>>(w, wsW);
    prep_const_kernel<<<1, 128, 0, stream>>>(bias, wsc);

    dim3 grid(5, 17, 32);   // q-tiles, p-tiles, n
    conv_main_kernel<<<grid, 256, SMEM_BYTES, stream>>>(x, bias, wsW, wsc, out);
}